// Round 16
// baseline (40.267 us; speedup 1.0000x reference)
//
#include <hip/hip_runtime.h>
#include <math.h>

// ---- DCT constants (fp32) ----
#define A0c 0.35355339059327373f
#define C1c 0.4903926402016152f
#define C2c 0.46193976625564337f
#define C3c 0.41573480615127262f
#define C5c 0.27778511650980114f
#define C6c 0.19134171618254492f
#define C7c 0.09754516100806417f

#define IMG_W 512
#define IMG_HW (512 * 512)

typedef float f8v __attribute__((ext_vector_type(8)));
typedef float f2v __attribute__((ext_vector_type(2)));

// base JPEG tables, ORIGINAL orientation (QUALITY=50 -> scaled == base)
__device__ const float QLUM[64] = {
    16,11,10,16,24,40,51,61,  12,12,14,19,26,58,60,55,
    14,13,16,24,40,57,69,56,  14,17,22,29,51,87,80,62,
    18,22,37,56,68,109,103,77, 24,35,55,64,81,104,113,92,
    49,64,78,87,103,121,120,101, 72,92,95,98,112,100,103,99};
__device__ const float QCHR[64] = {
    17,18,24,47,99,99,99,99,  18,21,26,66,99,99,99,99,
    24,26,56,99,99,99,99,99,  47,66,99,99,99,99,99,99,
    99,99,99,99,99,99,99,99,  99,99,99,99,99,99,99,99,
    99,99,99,99,99,99,99,99,  99,99,99,99,99,99,99,99};

// In-place 8-point DCT-II on PAIRS (textually identical to the R6-proven
// scalar form; <2 x float> arith maps to v_pk_*_f32, scalar consts splat free)
__device__ __forceinline__ void fdct8p(f2v v[8]) {
    f2v s0 = v[0] + v[7], s1 = v[1] + v[6], s2 = v[2] + v[5], s3 = v[3] + v[4];
    f2v d0 = v[0] - v[7], d1 = v[1] - v[6], d2 = v[2] - v[5], d3 = v[3] - v[4];
    f2v e0 = s0 + s3, e1 = s1 + s2, f0 = s0 - s3, f1 = s1 - s2;
    v[0] = A0c * (e0 + e1);
    v[4] = A0c * (e0 - e1);
    v[2] = C2c * f0 + C6c * f1;
    v[6] = C6c * f0 - C2c * f1;
    v[1] = C1c * d0 + C3c * d1 + C5c * d2 + C7c * d3;
    v[3] = C3c * d0 - C7c * d1 - C1c * d2 - C5c * d3;
    v[5] = C5c * d0 - C1c * d1 + C7c * d2 + C3c * d3;
    v[7] = C7c * d0 - C5c * d1 + C3c * d2 - C1c * d3;
}

__device__ __forceinline__ void idct8p(f2v v[8]) {
    f2v g0 = v[0], g1 = v[1], g2 = v[2], g3 = v[3];
    f2v g4 = v[4], g5 = v[5], g6 = v[6], g7 = v[7];
    f2v ep = A0c * (g0 + g4), em = A0c * (g0 - g4);
    f2v t26a = C2c * g2 + C6c * g6;
    f2v t26b = C6c * g2 - C2c * g6;
    f2v e0 = ep + t26a, e1 = em + t26b, e2 = em - t26b, e3 = ep - t26a;
    f2v o0 = C1c * g1 + C3c * g3 + C5c * g5 + C7c * g7;
    f2v o1 = C3c * g1 - C7c * g3 - C1c * g5 - C5c * g7;
    f2v o2 = C5c * g1 - C1c * g3 + C7c * g5 + C3c * g7;
    f2v o3 = C7c * g1 - C5c * g3 + C3c * g5 - C1c * g7;
    v[0] = e0 + o0; v[7] = e0 - o0;
    v[1] = e1 + o1; v[6] = e1 - o1;
    v[2] = e2 + o2; v[5] = e2 - o2;
    v[3] = e3 + o3; v[4] = e3 - o3;
}

// soft quantize-dequantize on a pair: deq = x + qh*tanh(15t), t = d - round(d).
// pk ops for mul/sub/fma; rint/exp2/rcp per element (no packed transcendentals).
#define K_EXP2 43.2808512266689f
__device__ __forceinline__ f2v softq2(f2v x, float qh, float rq) {
    f2v d = x * rq;
    f2v rn; rn[0] = rintf(d[0]); rn[1] = rintf(d[1]);
    f2v t = d - rn;
    f2v e2; e2[0] = __builtin_amdgcn_exp2f(K_EXP2 * t[0]);
            e2[1] = __builtin_amdgcn_exp2f(K_EXP2 * t[1]);
    f2v num = e2 - 1.0f;
    f2v th; th[0] = num[0] * __builtin_amdgcn_rcpf(e2[0] + 1.0f);
            th[1] = num[1] * __builtin_amdgcn_rcpf(e2[1] + 1.0f);
    return x + qh * th;
}

// compiler-only fence (R14-proven): forbids reordering LDS ops across it.
#define LDS_FENCE() asm volatile("" ::: "memory")

// One wave = TWO 64x8 tiles (images b and b+16) carried as f2v pairs.
// 3 channels serial, explicit (rule-#20). Zero __syncthreads. Skew-9
// transpose at 8B granularity: write xp[j*72+blk*9+row] (b64), read
// xp[row*72+blk*9+k] (b64) - both ~uniform across banks. Same 96 DS insts
// per wave as R14 but moving BOTH tiles: per-tile DS issue + lgkm stalls
// halve, load-latency amortizes 2x. qtab in LDS (R14-proven).
__global__ __launch_bounds__(256) void jpeg_kernel(const float* __restrict__ x,
                                                   float* __restrict__ out) {
    __shared__ f2v xpose[4][576];     // 18432 B
    __shared__ float qtab[4][64];     // 0:qhL 1:rqL 2:qhC 3:rqC, [v*8+u]

    const int tid = threadIdx.x;
    const int wid = tid >> 6;
    const int lane = tid & 63;

    const int gw = blockIdx.x * 4 + wid;     // 0..8191
    const int bimg = gw >> 9;                // image 0..15 (pair: +16)
    const int rem = gw & 511;
    const int gh = rem >> 3;                 // 8-row strip index
    const int tx = rem & 7;                  // 64-col tile index

    const int blk = lane & 7;                // 8x8 block within tile
    const int row = lane >> 3;               // row within strip / freq v

    const size_t off = (size_t)bimg * 3 * IMG_HW +
                       (size_t)(gh * 8 + row) * IMG_W + tx * 64 + blk * 8;
    const size_t toff = (size_t)16 * 3 * IMG_HW;
    const float* baseA = x + off;
    const float* baseB = baseA + toff;

    // issue all 6 global loads first; qtab init overlaps their latency
    const f8v RA = *(const f8v*)(baseA);
    const f8v GA = *(const f8v*)(baseA + IMG_HW);
    const f8v BA = *(const f8v*)(baseA + 2 * IMG_HW);
    const f8v RB = *(const f8v*)(baseB);
    const f8v GB = *(const f8v*)(baseB + IMG_HW);
    const f8v BB = *(const f8v*)(baseB + 2 * IMG_HW);

    {   // benign duplicate writes per wave; in-order DS per wave
        int u = lane & 7, v = lane >> 3;
        float ql = QLUM[u * 8 + v];
        float qc = QCHR[u * 8 + v];
        qtab[0][lane] = 0.5f * ql;
        qtab[1][lane] = __builtin_amdgcn_rcpf(ql);
        qtab[2][lane] = 0.5f * qc;
        qtab[3][lane] = __builtin_amdgcn_rcpf(qc);
    }
    LDS_FENCE();

    f2v* xp = xpose[wid];
    const int wbase = blk * 9 + row;         // write: xp[j*72 + wbase]
    const int rbase = row * 72 + blk * 9;    // read:  xp[rbase + k]
    const int qrow = row * 8;

    // ---- forward color (packed pairs across the two tiles) ----
    f2v g0[8], g1[8], g2[8];
#pragma unroll
    for (int k = 0; k < 8; ++k) {
        f2v Rp; Rp[0] = RA[k]; Rp[1] = RB[k];
        f2v Gp; Gp[0] = GA[k]; Gp[1] = GB[k];
        f2v Bp; Bp[0] = BA[k]; Bp[1] = BB[k];
        g0[k] = 0.299f * Rp + 0.587f * Gp + 0.114f * Bp - 0.5f;
        g1[k] = -0.168736f * Rp - 0.331264f * Gp + 0.5f * Bp;
        g2[k] = 0.5f * Rp - 0.418688f * Gp - 0.081312f * Bp;
    }

    // ================= channel 0 (luma) =================
    fdct8p(g0);
#pragma unroll
    for (int j = 0; j < 8; ++j) xp[j * 72 + wbase] = g0[j];
    LDS_FENCE();
#pragma unroll
    for (int k = 0; k < 8; ++k) g0[k] = xp[rbase + k];
    LDS_FENCE();
    fdct8p(g0);
    {
        float4 qa = *(const float4*)&qtab[0][qrow];
        float4 qb = *(const float4*)&qtab[0][qrow + 4];
        float4 ra = *(const float4*)&qtab[1][qrow];
        float4 rb = *(const float4*)&qtab[1][qrow + 4];
        g0[0] = softq2(g0[0], qa.x, ra.x); g0[1] = softq2(g0[1], qa.y, ra.y);
        g0[2] = softq2(g0[2], qa.z, ra.z); g0[3] = softq2(g0[3], qa.w, ra.w);
        g0[4] = softq2(g0[4], qb.x, rb.x); g0[5] = softq2(g0[5], qb.y, rb.y);
        g0[6] = softq2(g0[6], qb.z, rb.z); g0[7] = softq2(g0[7], qb.w, rb.w);
    }
    idct8p(g0);
    LDS_FENCE();
#pragma unroll
    for (int j = 0; j < 8; ++j) xp[j * 72 + wbase] = g0[j];
    LDS_FENCE();
#pragma unroll
    for (int k = 0; k < 8; ++k) g0[k] = xp[rbase + k];
    LDS_FENCE();
    idct8p(g0);

    // ================= channel 1 (Cb) =================
    fdct8p(g1);
#pragma unroll
    for (int j = 0; j < 8; ++j) xp[j * 72 + wbase] = g1[j];
    LDS_FENCE();
#pragma unroll
    for (int k = 0; k < 8; ++k) g1[k] = xp[rbase + k];
    LDS_FENCE();
    fdct8p(g1);
    {
        float4 qa = *(const float4*)&qtab[2][qrow];
        float4 qb = *(const float4*)&qtab[2][qrow + 4];
        float4 ra = *(const float4*)&qtab[3][qrow];
        float4 rb = *(const float4*)&qtab[3][qrow + 4];
        g1[0] = softq2(g1[0], qa.x, ra.x); g1[1] = softq2(g1[1], qa.y, ra.y);
        g1[2] = softq2(g1[2], qa.z, ra.z); g1[3] = softq2(g1[3], qa.w, ra.w);
        g1[4] = softq2(g1[4], qb.x, rb.x); g1[5] = softq2(g1[5], qb.y, rb.y);
        g1[6] = softq2(g1[6], qb.z, rb.z); g1[7] = softq2(g1[7], qb.w, rb.w);
    }
    idct8p(g1);
    LDS_FENCE();
#pragma unroll
    for (int j = 0; j < 8; ++j) xp[j * 72 + wbase] = g1[j];
    LDS_FENCE();
#pragma unroll
    for (int k = 0; k < 8; ++k) g1[k] = xp[rbase + k];
    LDS_FENCE();
    idct8p(g1);

    // ================= channel 2 (Cr) =================
    fdct8p(g2);
#pragma unroll
    for (int j = 0; j < 8; ++j) xp[j * 72 + wbase] = g2[j];
    LDS_FENCE();
#pragma unroll
    for (int k = 0; k < 8; ++k) g2[k] = xp[rbase + k];
    LDS_FENCE();
    fdct8p(g2);
    {
        float4 qa = *(const float4*)&qtab[2][qrow];
        float4 qb = *(const float4*)&qtab[2][qrow + 4];
        float4 ra = *(const float4*)&qtab[3][qrow];
        float4 rb = *(const float4*)&qtab[3][qrow + 4];
        g2[0] = softq2(g2[0], qa.x, ra.x); g2[1] = softq2(g2[1], qa.y, ra.y);
        g2[2] = softq2(g2[2], qa.z, ra.z); g2[3] = softq2(g2[3], qa.w, ra.w);
        g2[4] = softq2(g2[4], qb.x, rb.x); g2[5] = softq2(g2[5], qb.y, rb.y);
        g2[6] = softq2(g2[6], qb.z, rb.z); g2[7] = softq2(g2[7], qb.w, rb.w);
    }
    idct8p(g2);
    LDS_FENCE();
#pragma unroll
    for (int j = 0; j < 8; ++j) xp[j * 72 + wbase] = g2[j];
    LDS_FENCE();
#pragma unroll
    for (int k = 0; k < 8; ++k) g2[k] = xp[rbase + k];
    LDS_FENCE();
    idct8p(g2);

    // ---- inverse color (packed) + split + coalesced stores ----
    const f2v vzero = {0.0f, 0.0f};
    const f2v vone  = {1.0f, 1.0f};
    f8v RoA, GoA, BoA, RoB, GoB, BoB;
#pragma unroll
    for (int k = 0; k < 8; ++k) {
        f2v Y  = g0[k] + 0.5f;
        f2v Cb = g1[k];
        f2v Cr = g2[k];
        f2v R = Y + 1.402f * Cr;
        f2v G = Y - 0.344136f * Cb - 0.714136f * Cr;
        f2v B = Y + 1.772f * Cb;
        R = __builtin_elementwise_min(__builtin_elementwise_max(R, vzero), vone);
        G = __builtin_elementwise_min(__builtin_elementwise_max(G, vzero), vone);
        B = __builtin_elementwise_min(__builtin_elementwise_max(B, vzero), vone);
        RoA[k] = R[0]; RoB[k] = R[1];
        GoA[k] = G[0]; GoB[k] = G[1];
        BoA[k] = B[0]; BoB[k] = B[1];
    }
    float* oA = out + off;
    float* oB = oA + toff;
    *(f8v*)(oA) = RoA;
    *(f8v*)(oA + IMG_HW) = GoA;
    *(f8v*)(oA + 2 * IMG_HW) = BoA;
    *(f8v*)(oB) = RoB;
    *(f8v*)(oB + IMG_HW) = GoB;
    *(f8v*)(oB + 2 * IMG_HW) = BoB;
}

extern "C" void kernel_launch(void* const* d_in, const int* in_sizes, int n_in,
                              void* d_out, int out_size, void* d_ws, size_t ws_size,
                              hipStream_t stream) {
    const float* x = (const float*)d_in[0];
    float* out = (float*)d_out;
    // 8192 waves x 2 tiles = 16384 tiles (32 images x 512 tiles each)
    const int n_wg = 2048;
    hipLaunchKernelGGL(jpeg_kernel, dim3(n_wg), dim3(256), 0, stream, x, out);
}

// Round 17
// 39.029 us; speedup vs baseline: 1.0317x; 1.0317x over previous
//
#include <hip/hip_runtime.h>
#include <math.h>

// ---- DCT constants (fp32) ----
#define A0c 0.35355339059327373f
#define C1c 0.4903926402016152f
#define C2c 0.46193976625564337f
#define C3c 0.41573480615127262f
#define C5c 0.27778511650980114f
#define C6c 0.19134171618254492f
#define C7c 0.09754516100806417f

#define IMG_W 512
#define IMG_HW (512 * 512)

typedef float f8v __attribute__((ext_vector_type(8)));

// base JPEG tables, ORIGINAL orientation (QUALITY=50 -> scaled == base)
__device__ const float QLUM[64] = {
    16,11,10,16,24,40,51,61,  12,12,14,19,26,58,60,55,
    14,13,16,24,40,57,69,56,  14,17,22,29,51,87,80,62,
    18,22,37,56,68,109,103,77, 24,35,55,64,81,104,113,92,
    49,64,78,87,103,121,120,101, 72,92,95,98,112,100,103,99};
__device__ const float QCHR[64] = {
    17,18,24,47,99,99,99,99,  18,21,26,66,99,99,99,99,
    24,26,56,99,99,99,99,99,  47,66,99,99,99,99,99,99,
    99,99,99,99,99,99,99,99,  99,99,99,99,99,99,99,99,
    99,99,99,99,99,99,99,99,  99,99,99,99,99,99,99,99};

// In-place 8-point DCT-II (scalar, R6/R14-proven)
__device__ __forceinline__ void fdct8(float v[8]) {
    float s0 = v[0] + v[7], s1 = v[1] + v[6], s2 = v[2] + v[5], s3 = v[3] + v[4];
    float d0 = v[0] - v[7], d1 = v[1] - v[6], d2 = v[2] - v[5], d3 = v[3] - v[4];
    float e0 = s0 + s3, e1 = s1 + s2, f0 = s0 - s3, f1 = s1 - s2;
    v[0] = A0c * (e0 + e1);
    v[4] = A0c * (e0 - e1);
    v[2] = C2c * f0 + C6c * f1;
    v[6] = C6c * f0 - C2c * f1;
    v[1] = C1c * d0 + C3c * d1 + C5c * d2 + C7c * d3;
    v[3] = C3c * d0 - C7c * d1 - C1c * d2 - C5c * d3;
    v[5] = C5c * d0 - C1c * d1 + C7c * d2 + C3c * d3;
    v[7] = C7c * d0 - C5c * d1 + C3c * d2 - C1c * d3;
}

// In-place 8-point inverse (scalar, R6/R14-proven)
__device__ __forceinline__ void idct8(float v[8]) {
    float g0 = v[0], g1 = v[1], g2 = v[2], g3 = v[3];
    float g4 = v[4], g5 = v[5], g6 = v[6], g7 = v[7];
    float ep = A0c * (g0 + g4), em = A0c * (g0 - g4);
    float t26a = C2c * g2 + C6c * g6;
    float t26b = C6c * g2 - C2c * g6;
    float e0 = ep + t26a, e1 = em + t26b, e2 = em - t26b, e3 = ep - t26a;
    float o0 = C1c * g1 + C3c * g3 + C5c * g5 + C7c * g7;
    float o1 = C3c * g1 - C7c * g3 - C1c * g5 - C5c * g7;
    float o2 = C5c * g1 - C1c * g3 + C7c * g5 + C3c * g7;
    float o3 = C7c * g1 - C5c * g3 + C3c * g5 - C1c * g7;
    v[0] = e0 + o0; v[7] = e0 - o0;
    v[1] = e1 + o1; v[6] = e1 - o1;
    v[2] = e2 + o2; v[5] = e2 - o2;
    v[3] = e3 + o3; v[4] = e3 - o3;
}

// soft quantize-dequantize: deq = x + qh*tanh(15t), qh = 0.5q, t = d - round(d)
#define K_EXP2 43.2808512266689f
__device__ __forceinline__ float softq(float x, float qh, float rq) {
    float d = x * rq;
    float rn = rintf(d);                   // nearest-even, matches jnp.round
    float t = d - rn;
    float e2 = __builtin_amdgcn_exp2f(K_EXP2 * t);
    float th = (e2 - 1.0f) * __builtin_amdgcn_rcpf(e2 + 1.0f);
    return x + qh * th;
}

// compiler-only fence (R14-proven): no memory op may be reordered across it.
#define LDS_FENCE() asm volatile("" ::: "memory")

// per-channel chain: H-DCT, LDS transpose, V-DCT, softq, V-iDCT, LDS
// transpose, H-iDCT. Skew-9, wave-private region, fences at every burst.
__device__ __forceinline__ void chan_chain(float g[8], float* xp, int wbase,
                                           int rbase, const float* qh8,
                                           const float* rq8) {
    fdct8(g);
#pragma unroll
    for (int j = 0; j < 8; ++j) xp[j * 72 + wbase] = g[j];
    LDS_FENCE();
#pragma unroll
    for (int k = 0; k < 8; ++k) g[k] = xp[rbase + k];
    LDS_FENCE();
    fdct8(g);
    {
        float4 qa = *(const float4*)&qh8[0];
        float4 qb = *(const float4*)&qh8[4];
        float4 ra = *(const float4*)&rq8[0];
        float4 rb = *(const float4*)&rq8[4];
        g[0] = softq(g[0], qa.x, ra.x); g[1] = softq(g[1], qa.y, ra.y);
        g[2] = softq(g[2], qa.z, ra.z); g[3] = softq(g[3], qa.w, ra.w);
        g[4] = softq(g[4], qb.x, rb.x); g[5] = softq(g[5], qb.y, rb.y);
        g[6] = softq(g[6], qb.z, rb.z); g[7] = softq(g[7], qb.w, rb.w);
    }
    idct8(g);
    LDS_FENCE();
#pragma unroll
    for (int j = 0; j < 8; ++j) xp[j * 72 + wbase] = g[j];
    LDS_FENCE();
#pragma unroll
    for (int k = 0; k < 8; ++k) g[k] = xp[rbase + k];
    LDS_FENCE();
    idct8(g);
}

// full per-tile body (R14-proven): forward color, 3 channel chains, inverse
// color, coalesced stores. Distinct call sites -> full inlining, no rule-#20.
__device__ __forceinline__ void process_tile(const f8v Rv, const f8v Gv, const f8v Bv,
                                             float* xp, int wbase, int rbase,
                                             const float* qt0, const float* qt1,
                                             const float* qt2, const float* qt3,
                                             float* obase) {
    float g0[8], g1[8], g2[8];
#pragma unroll
    for (int k = 0; k < 8; ++k) {
        float R = Rv[k], G = Gv[k], B = Bv[k];
        g0[k] = 0.299f * R + 0.587f * G + 0.114f * B - 0.5f;
        g1[k] = -0.168736f * R - 0.331264f * G + 0.5f * B;
        g2[k] = 0.5f * R - 0.418688f * G - 0.081312f * B;
    }
    chan_chain(g0, xp, wbase, rbase, qt0, qt1);
    chan_chain(g1, xp, wbase, rbase, qt2, qt3);
    chan_chain(g2, xp, wbase, rbase, qt2, qt3);

    f8v Ro, Go, Bo;
#pragma unroll
    for (int k = 0; k < 8; ++k) {
        float Y  = g0[k] + 0.5f;
        float Cb = g1[k];
        float Cr = g2[k];
        float R = Y + 1.402f * Cr;
        float G = Y - 0.344136f * Cb - 0.714136f * Cr;
        float B = Y + 1.772f * Cb;
        Ro[k] = fminf(fmaxf(R, 0.0f), 1.0f);
        Go[k] = fminf(fmaxf(G, 0.0f), 1.0f);
        Bo[k] = fminf(fmaxf(B, 0.0f), 1.0f);
    }
    *(f8v*)(obase) = Ro;
    *(f8v*)(obase + IMG_HW) = Go;
    *(f8v*)(obase + 2 * IMG_HW) = Bo;
}

// One wave = FOUR tiles (images b, b+8, b+16, b+24; same strip/col position),
// software-pipelined: next tile's 3 loads issue BEFORE current tile's compute
// and stay in flight under it (pin via asm clobber - R9-proven). Grid = one
// residency round (4 waves/SIMD); after the small tile-0 burst (25 MB), HBM
// load traffic streams continuously under compute instead of convoying.
__global__ __launch_bounds__(256) void jpeg_kernel(const float* __restrict__ x,
                                                   float* __restrict__ out) {
    __shared__ float xpose[4][576];   // per-wave transpose scratch (9216 B)
    __shared__ float qtab[4][64];     // 0:qhL 1:rqL 2:qhC 3:rqC, [v*8+u]

    const int tid = threadIdx.x;
    const int wid = tid >> 6;
    const int lane = tid & 63;

    const int gw = blockIdx.x * 4 + wid;     // 0..4095
    const int bimg = gw >> 9;                // image 0..7 (tiles: +8,+16,+24)
    const int rem = gw & 511;
    const int gh = rem >> 3;                 // 8-row strip index
    const int tx = rem & 7;                  // 64-col tile index

    const int blk = lane & 7;                // 8x8 block within tile
    const int row = lane >> 3;               // row within strip / freq v

    const size_t off0 = (size_t)bimg * 3 * IMG_HW +
                        (size_t)(gh * 8 + row) * IMG_W + tx * 64 + blk * 8;
    const size_t DOFF = (size_t)8 * 3 * IMG_HW;   // +8 images

    // ---- tile 0 loads ----
    f8v Rc = *(const f8v*)(x + off0);
    f8v Gc = *(const f8v*)(x + off0 + IMG_HW);
    f8v Bc = *(const f8v*)(x + off0 + 2 * IMG_HW);

    // qtab init overlaps tile-0 load latency (benign duplicate writes)
    {
        int u = lane & 7, v = lane >> 3;
        float ql = QLUM[u * 8 + v];
        float qc = QCHR[u * 8 + v];
        qtab[0][lane] = 0.5f * ql;
        qtab[1][lane] = __builtin_amdgcn_rcpf(ql);
        qtab[2][lane] = 0.5f * qc;
        qtab[3][lane] = __builtin_amdgcn_rcpf(qc);
    }
    LDS_FENCE();

    float* xp = xpose[wid];
    const int wbase = blk * 9 + row;
    const int rbase = row * 72 + blk * 9;
    const int qrow = row * 8;
    const float* qt0 = &qtab[0][qrow];
    const float* qt1 = &qtab[1][qrow];
    const float* qt2 = &qtab[2][qrow];
    const float* qt3 = &qtab[3][qrow];

    // ================= iter 0: prefetch tile 1, compute tile 0 =============
    f8v Rn = *(const f8v*)(x + off0 + DOFF);
    f8v Gn = *(const f8v*)(x + off0 + DOFF + IMG_HW);
    f8v Bn = *(const f8v*)(x + off0 + DOFF + 2 * IMG_HW);
    LDS_FENCE();   // pin prefetch before compute
    process_tile(Rc, Gc, Bc, xp, wbase, rbase, qt0, qt1, qt2, qt3, out + off0);
    Rc = Rn; Gc = Gn; Bc = Bn;

    // ================= iter 1: prefetch tile 2, compute tile 1 =============
    Rn = *(const f8v*)(x + off0 + 2 * DOFF);
    Gn = *(const f8v*)(x + off0 + 2 * DOFF + IMG_HW);
    Bn = *(const f8v*)(x + off0 + 2 * DOFF + 2 * IMG_HW);
    LDS_FENCE();
    process_tile(Rc, Gc, Bc, xp, wbase, rbase, qt0, qt1, qt2, qt3, out + off0 + DOFF);
    Rc = Rn; Gc = Gn; Bc = Bn;

    // ================= iter 2: prefetch tile 3, compute tile 2 =============
    Rn = *(const f8v*)(x + off0 + 3 * DOFF);
    Gn = *(const f8v*)(x + off0 + 3 * DOFF + IMG_HW);
    Bn = *(const f8v*)(x + off0 + 3 * DOFF + 2 * IMG_HW);
    LDS_FENCE();
    process_tile(Rc, Gc, Bc, xp, wbase, rbase, qt0, qt1, qt2, qt3, out + off0 + 2 * DOFF);
    Rc = Rn; Gc = Gn; Bc = Bn;

    // ================= iter 3: compute tile 3 (no prefetch) ================
    process_tile(Rc, Gc, Bc, xp, wbase, rbase, qt0, qt1, qt2, qt3, out + off0 + 3 * DOFF);
}

extern "C" void kernel_launch(void* const* d_in, const int* in_sizes, int n_in,
                              void* d_out, int out_size, void* d_ws, size_t ws_size,
                              hipStream_t stream) {
    const float* x = (const float*)d_in[0];
    float* out = (float*)d_out;
    // 4096 waves x 4 tiles = 16384 tiles (32 images x 512 tiles each)
    const int n_wg = 1024;
    hipLaunchKernelGGL(jpeg_kernel, dim3(n_wg), dim3(256), 0, stream, x, out);
}